// Round 1
// baseline (1739.354 us; speedup 1.0000x reference)
//
#include <hip/hip_runtime.h>
#include <cstddef>

#define NN 100000
#define NE 600000
#define HID 128

// ---------------------------------------------------------------- degree
__global__ void k_deg(const int* __restrict__ col, float* __restrict__ deg, int E) {
    int e = blockIdx.x * blockDim.x + threadIdx.x;
    if (e < E) atomicAdd(&deg[col[e]], 1.0f);
}

// dinv = deg>0 ? rsqrt(deg) : 0   (in place)
__global__ void k_dinv(float* __restrict__ deg, int N) {
    int i = blockIdx.x * blockDim.x + threadIdx.x;
    if (i < N) {
        float d = deg[i];
        deg[i] = d > 0.0f ? rsqrtf(d) : 0.0f;
    }
}

__global__ void k_norm(const int* __restrict__ row, const int* __restrict__ col,
                       const float* __restrict__ dinv, float* __restrict__ norm, int E) {
    int e = blockIdx.x * blockDim.x + threadIdx.x;
    if (e < E) norm[e] = dinv[row[e]] * dinv[col[e]];
}

// fill out[r][c] = bias[c]
__global__ void k_fill_bias(float* __restrict__ out, const float* __restrict__ bias, int n4) {
    int i = blockIdx.x * blockDim.x + threadIdx.x;   // float4 index
    if (i >= n4) return;
    int c4 = i & 31;                                 // 32 float4 per 128-wide row
    ((float4*)out)[i] = ((const float4*)bias)[c4];
}

// ---------------------------------------------------------------- GEMM
// H = act(A) @ W ; act(x) = bias ? relu(x + bias) : x
// tile: 128 rows x 128 cols per 256-thread block, 8x8 per thread, k-chunk 64
constexpr int BM = 128;
constexpr int KC = 64;
constexpr int XS = 132;   // padded stride for transposed x tile (f4-aligned)

__global__ __launch_bounds__(256, 2) void k_gemm(
    const float* __restrict__ A, const float* __restrict__ W,
    const float* __restrict__ bias, float* __restrict__ H, int nrows)
{
    __shared__ float ws[KC][HID];    // W[kchunk][128]        32 KB
    __shared__ float xsT[KC][XS];    // x transposed [k][row] 33 KB
    const int tid  = threadIdx.x;
    const int row0 = blockIdx.x * BM;
    const int rg   = tid >> 4;   // 0..15 row group (8 rows)
    const int cg   = tid & 15;   // 0..15 col group (8 cols)

    float acc[8][8];
    #pragma unroll
    for (int i = 0; i < 8; ++i)
        #pragma unroll
        for (int j = 0; j < 8; ++j) acc[i][j] = 0.0f;

    for (int kc = 0; kc < HID; kc += KC) {
        __syncthreads();
        // stage W chunk: 64x128 floats = 2048 f4, 8 f4/thread, coalesced
        #pragma unroll
        for (int i = 0; i < 8; ++i) {
            int j = tid + i * 256;
            int k = j >> 5, c4 = j & 31;
            float4 v = ((const float4*)(W + (size_t)(kc + k) * HID))[c4];
            *(float4*)&ws[k][c4 * 4] = v;
        }
        // stage x chunk transposed (apply fused bias+relu of previous layer)
        #pragma unroll
        for (int i = 0; i < 8; ++i) {
            int j = tid + i * 256;
            int r = j >> 4, kq = j & 15;
            int gr = row0 + r; if (gr >= nrows) gr = nrows - 1;
            float4 v = ((const float4*)(A + (size_t)gr * HID + kc))[kq];
            if (bias) {
                int kb = kc + kq * 4;
                v.x = fmaxf(v.x + bias[kb + 0], 0.0f);
                v.y = fmaxf(v.y + bias[kb + 1], 0.0f);
                v.z = fmaxf(v.z + bias[kb + 2], 0.0f);
                v.w = fmaxf(v.w + bias[kb + 3], 0.0f);
            }
            xsT[kq * 4 + 0][r] = v.x;
            xsT[kq * 4 + 1][r] = v.y;
            xsT[kq * 4 + 2][r] = v.z;
            xsT[kq * 4 + 3][r] = v.w;
        }
        __syncthreads();
        #pragma unroll 2
        for (int k = 0; k < KC; ++k) {
            float xv[8], wv[8];
            *(float4*)&xv[0] = *(const float4*)&xsT[k][rg * 8];
            *(float4*)&xv[4] = *(const float4*)&xsT[k][rg * 8 + 4];
            *(float4*)&wv[0] = *(const float4*)&ws[k][cg * 8];
            *(float4*)&wv[4] = *(const float4*)&ws[k][cg * 8 + 4];
            #pragma unroll
            for (int i = 0; i < 8; ++i)
                #pragma unroll
                for (int jj = 0; jj < 8; ++jj)
                    acc[i][jj] = fmaf(xv[i], wv[jj], acc[i][jj]);
        }
    }
    #pragma unroll
    for (int i = 0; i < 8; ++i) {
        int r = row0 + rg * 8 + i;
        if (r < nrows) {
            float4 o0 = make_float4(acc[i][0], acc[i][1], acc[i][2], acc[i][3]);
            float4 o1 = make_float4(acc[i][4], acc[i][5], acc[i][6], acc[i][7]);
            float4* dst = (float4*)(H + (size_t)r * HID + cg * 8);
            dst[0] = o0; dst[1] = o1;
        }
    }
}

// ---------------------------------------------------------------- scatter
// one wave per edge: agg[col] += h[row] * norm  (128 f32 atomics/edge)
__global__ void k_scatter(const float* __restrict__ h, const int* __restrict__ row,
                          const int* __restrict__ col, const float* __restrict__ norm,
                          float* __restrict__ agg, int E)
{
    int gid  = blockIdx.x * blockDim.x + threadIdx.x;
    int e    = gid >> 6;
    int lane = gid & 63;
    if (e >= E) return;
    int r = row[e], c = col[e];
    float nm = norm[e];
    float2 v = *(const float2*)(h + (size_t)r * HID + lane * 2);
    float* dst = agg + (size_t)c * HID + lane * 2;
    atomicAdd(dst,     v.x * nm);
    atomicAdd(dst + 1, v.y * nm);
}

// ---------------------------------------------------------------- launch
extern "C" void kernel_launch(void* const* d_in, const int* in_sizes, int n_in,
                              void* d_out, int out_size, void* d_ws, size_t ws_size,
                              hipStream_t stream)
{
    const float* x  = (const float*)d_in[0];
    const float* W1 = (const float*)d_in[1];
    const float* b1 = (const float*)d_in[2];
    const float* W2 = (const float*)d_in[3];
    const float* b2 = (const float*)d_in[4];
    const float* W3 = (const float*)d_in[5];
    const float* b3 = (const float*)d_in[6];
    const int*   ei = (const int*)d_in[7];
    const int* row  = ei;            // edge_index[0]
    const int* colv = ei + NE;       // edge_index[1]
    float* out = (float*)d_out;

    float* wsf  = (float*)d_ws;
    float* deg  = wsf;               // NN floats (becomes dinv in place)
    float* norm = wsf + NN;          // NE floats
    float* h    = wsf + NN + NE;     // NN*HID floats (51.2 MB)

    const int TB = 256;
    const size_t outBytes = (size_t)NN * HID * sizeof(float);

    // normalization
    hipMemsetAsync(deg, 0, NN * sizeof(float), stream);
    k_deg <<<(NE + TB - 1) / TB, TB, 0, stream>>>(colv, deg, NE);
    k_dinv<<<(NN + TB - 1) / TB, TB, 0, stream>>>(deg, NN);
    k_norm<<<(NE + TB - 1) / TB, TB, 0, stream>>>(row, colv, deg, norm, NE);

    const int gemmBlocks = (NN + BM - 1) / BM;       // 782
    const int scatBlocks = (NE * 64 + TB - 1) / TB;  // 150000
    const int fillN4     = NN * (HID / 4);           // 3.2M float4
    const int fillBlocks = (fillN4 + TB - 1) / TB;

    // ---- layer 1: h = x@W1 ; out = scatter(h) (agg1, bias deferred)
    k_gemm<<<gemmBlocks, TB, 0, stream>>>(x, W1, nullptr, h, NN);
    hipMemsetAsync(out, 0, outBytes, stream);
    k_scatter<<<scatBlocks, TB, 0, stream>>>(h, row, colv, norm, out, NE);

    // ---- layer 2: h = relu(out+b1)@W2 ; out = scatter(h) (agg2)
    k_gemm<<<gemmBlocks, TB, 0, stream>>>(out, W2, b1, h, NN);
    hipMemsetAsync(out, 0, outBytes, stream);
    k_scatter<<<scatBlocks, TB, 0, stream>>>(h, row, colv, norm, out, NE);

    // ---- layer 3: h = relu(out+b2)@W3 ; out = b3 + scatter(h)
    k_gemm<<<gemmBlocks, TB, 0, stream>>>(out, W3, b2, h, NN);
    k_fill_bias<<<fillBlocks, TB, 0, stream>>>(out, b3, fillN4);
    k_scatter<<<scatBlocks, TB, 0, stream>>>(h, row, colv, norm, out, NE);
}

// Round 2
// 457.868 us; speedup vs baseline: 3.7988x; 3.7988x over previous
//
#include <hip/hip_runtime.h>
#include <cstddef>

#define NN 100000
#define NE 600000
#define HID 128

// ---------------------------------------------------------------- degree (int)
__global__ void k_degi(const int* __restrict__ col, int* __restrict__ degi, int E) {
    int e = blockIdx.x * blockDim.x + threadIdx.x;
    if (e < E) atomicAdd(&degi[col[e]], 1);
}

__global__ void k_dinv(const int* __restrict__ degi, float* __restrict__ dinv, int N) {
    int i = blockIdx.x * blockDim.x + threadIdx.x;
    if (i < N) {
        int d = degi[i];
        dinv[i] = d > 0 ? rsqrtf((float)d) : 0.0f;
    }
}

// ---------------------------------------------------------------- prefix scan (3-phase)
__global__ void k_blocksum(const int* __restrict__ degi, int* __restrict__ bsum, int N) {
    __shared__ int sh[256];
    int i = blockIdx.x * 256 + threadIdx.x;
    sh[threadIdx.x] = i < N ? degi[i] : 0;
    __syncthreads();
    for (int s = 128; s > 0; s >>= 1) {
        if (threadIdx.x < s) sh[threadIdx.x] += sh[threadIdx.x + s];
        __syncthreads();
    }
    if (threadIdx.x == 0) bsum[blockIdx.x] = sh[0];
}

__global__ void k_scan_bsum(int* __restrict__ bsum, int nb) {
    if (threadIdx.x == 0 && blockIdx.x == 0) {
        int acc = 0;
        for (int i = 0; i < nb; ++i) { int v = bsum[i]; bsum[i] = acc; acc += v; }
    }
}

__global__ void k_scan_apply(const int* __restrict__ degi, const int* __restrict__ bsum,
                             int* __restrict__ rowptr, int* __restrict__ cursor, int N) {
    __shared__ int sh[256];
    int i = blockIdx.x * 256 + threadIdx.x;
    int v = (i < N) ? degi[i] : 0;
    sh[threadIdx.x] = v;
    __syncthreads();
    #pragma unroll
    for (int s = 1; s < 256; s <<= 1) {
        int t = (threadIdx.x >= s) ? sh[threadIdx.x - s] : 0;
        __syncthreads();
        sh[threadIdx.x] += t;
        __syncthreads();
    }
    if (i < N) {
        int excl = bsum[blockIdx.x] + sh[threadIdx.x] - v;
        rowptr[i] = excl;
        cursor[i] = excl;
        if (i == N - 1) rowptr[N] = bsum[blockIdx.x] + sh[threadIdx.x];
    }
}

// bucket-fill: csr slot = absolute position from cursor
__global__ void k_fill_csr(const int* __restrict__ row, const int* __restrict__ col,
                           const float* __restrict__ dinv, int* __restrict__ cursor,
                           int* __restrict__ csr_src, float* __restrict__ csr_norm, int E) {
    int e = blockIdx.x * blockDim.x + threadIdx.x;
    if (e >= E) return;
    int r = row[e], c = col[e];
    int pos = atomicAdd(&cursor[c], 1);
    csr_src[pos]  = r;
    csr_norm[pos] = dinv[r] * dinv[c];
}

// ---------------------------------------------------------------- GEMM
// H = act(A) @ W ; act(x) = bias ? relu(x + bias) : x
constexpr int BM = 128;
constexpr int KC = 64;
constexpr int XS = 132;

__global__ __launch_bounds__(256, 2) void k_gemm(
    const float* __restrict__ A, const float* __restrict__ W,
    const float* __restrict__ bias, float* __restrict__ H, int nrows)
{
    __shared__ float ws[KC][HID];
    __shared__ float xsT[KC][XS];
    const int tid  = threadIdx.x;
    const int row0 = blockIdx.x * BM;
    const int rg   = tid >> 4;
    const int cg   = tid & 15;

    float acc[8][8];
    #pragma unroll
    for (int i = 0; i < 8; ++i)
        #pragma unroll
        for (int j = 0; j < 8; ++j) acc[i][j] = 0.0f;

    for (int kc = 0; kc < HID; kc += KC) {
        __syncthreads();
        #pragma unroll
        for (int i = 0; i < 8; ++i) {
            int j = tid + i * 256;
            int k = j >> 5, c4 = j & 31;
            float4 v = ((const float4*)(W + (size_t)(kc + k) * HID))[c4];
            *(float4*)&ws[k][c4 * 4] = v;
        }
        #pragma unroll
        for (int i = 0; i < 8; ++i) {
            int j = tid + i * 256;
            int r = j >> 4, kq = j & 15;
            int gr = row0 + r; if (gr >= nrows) gr = nrows - 1;
            float4 v = ((const float4*)(A + (size_t)gr * HID + kc))[kq];
            if (bias) {
                int kb = kc + kq * 4;
                v.x = fmaxf(v.x + bias[kb + 0], 0.0f);
                v.y = fmaxf(v.y + bias[kb + 1], 0.0f);
                v.z = fmaxf(v.z + bias[kb + 2], 0.0f);
                v.w = fmaxf(v.w + bias[kb + 3], 0.0f);
            }
            xsT[kq * 4 + 0][r] = v.x;
            xsT[kq * 4 + 1][r] = v.y;
            xsT[kq * 4 + 2][r] = v.z;
            xsT[kq * 4 + 3][r] = v.w;
        }
        __syncthreads();
        #pragma unroll 2
        for (int k = 0; k < KC; ++k) {
            float xv[8], wv[8];
            *(float4*)&xv[0] = *(const float4*)&xsT[k][rg * 8];
            *(float4*)&xv[4] = *(const float4*)&xsT[k][rg * 8 + 4];
            *(float4*)&wv[0] = *(const float4*)&ws[k][cg * 8];
            *(float4*)&wv[4] = *(const float4*)&ws[k][cg * 8 + 4];
            #pragma unroll
            for (int i = 0; i < 8; ++i)
                #pragma unroll
                for (int jj = 0; jj < 8; ++jj)
                    acc[i][jj] = fmaf(xv[i], wv[jj], acc[i][jj]);
        }
    }
    #pragma unroll
    for (int i = 0; i < 8; ++i) {
        int r = row0 + rg * 8 + i;
        if (r < nrows) {
            float4 o0 = make_float4(acc[i][0], acc[i][1], acc[i][2], acc[i][3]);
            float4 o1 = make_float4(acc[i][4], acc[i][5], acc[i][6], acc[i][7]);
            float4* dst = (float4*)(H + (size_t)r * HID + cg * 8);
            dst[0] = o0; dst[1] = o1;
        }
    }
}

// ---------------------------------------------------------------- aggregate (CSR gather)
// one wave per target node; lane holds float2 of the 128-wide feature row
__global__ __launch_bounds__(256) void k_aggregate(
    const float* __restrict__ h, const int* __restrict__ csr_src,
    const float* __restrict__ csr_norm, const int* __restrict__ rowptr,
    const float* __restrict__ bias, float* __restrict__ agg, int N)
{
    int node = blockIdx.x * 4 + (threadIdx.x >> 6);
    if (node >= N) return;
    int lane = threadIdx.x & 63;
    int beg = rowptr[node], end = rowptr[node + 1];
    float accx = 0.0f, accy = 0.0f;
    int i = beg;
    // 2-wide manual unroll: two independent gathers in flight
    for (; i + 1 < end; i += 2) {
        int   s0 = csr_src[i],     s1 = csr_src[i + 1];
        float n0 = csr_norm[i],    n1 = csr_norm[i + 1];
        float2 v0 = *(const float2*)(h + (size_t)s0 * HID + lane * 2);
        float2 v1 = *(const float2*)(h + (size_t)s1 * HID + lane * 2);
        accx = fmaf(v0.x, n0, accx); accy = fmaf(v0.y, n0, accy);
        accx = fmaf(v1.x, n1, accx); accy = fmaf(v1.y, n1, accy);
    }
    if (i < end) {
        int   s0 = csr_src[i];
        float n0 = csr_norm[i];
        float2 v0 = *(const float2*)(h + (size_t)s0 * HID + lane * 2);
        accx = fmaf(v0.x, n0, accx); accy = fmaf(v0.y, n0, accy);
    }
    if (bias) {
        float2 bv = *(const float2*)(bias + lane * 2);
        accx += bv.x; accy += bv.y;
    }
    *(float2*)(agg + (size_t)node * HID + lane * 2) = make_float2(accx, accy);
}

// ---------------------------------------------------------------- launch
extern "C" void kernel_launch(void* const* d_in, const int* in_sizes, int n_in,
                              void* d_out, int out_size, void* d_ws, size_t ws_size,
                              hipStream_t stream)
{
    const float* x  = (const float*)d_in[0];
    const float* W1 = (const float*)d_in[1];
    const float* b1 = (const float*)d_in[2];
    const float* W2 = (const float*)d_in[3];
    const float* b2 = (const float*)d_in[4];
    const float* W3 = (const float*)d_in[5];
    const float* b3 = (const float*)d_in[6];
    const int*   ei = (const int*)d_in[7];
    const int* row  = ei;            // edge_index[0] (sources)
    const int* colv = ei + NE;       // edge_index[1] (targets)
    float* out = (float*)d_out;

    // ws layout: h first (16B aligned), then int/float scratch
    float* h        = (float*)d_ws;                 // NN*HID floats (51.2 MB)
    int*   degi     = (int*)(h + (size_t)NN * HID); // NN
    float* dinv     = (float*)(degi + NN);          // NN
    int*   rowptr   = (int*)(dinv + NN);            // NN+1
    int*   cursor   = rowptr + NN + 1;              // NN
    int*   bsum     = cursor + NN;                  // <=400
    int*   csr_src  = bsum + 400;                   // NE
    float* csr_norm = (float*)(csr_src + NE);       // NE

    const int TB = 256;
    const int nScanBlocks = (NN + 255) / 256;       // 391

    // ---- CSR build (per-launch; edges constant)
    hipMemsetAsync(degi, 0, NN * sizeof(int), stream);
    k_degi     <<<(NE + TB - 1) / TB, TB, 0, stream>>>(colv, degi, NE);
    k_dinv     <<<(NN + TB - 1) / TB, TB, 0, stream>>>(degi, dinv, NN);
    k_blocksum <<<nScanBlocks, 256, 0, stream>>>(degi, bsum, NN);
    k_scan_bsum<<<1, 64, 0, stream>>>(bsum, nScanBlocks);
    k_scan_apply<<<nScanBlocks, 256, 0, stream>>>(degi, bsum, rowptr, cursor, NN);
    k_fill_csr <<<(NE + TB - 1) / TB, TB, 0, stream>>>(row, colv, dinv, cursor,
                                                       csr_src, csr_norm, NE);

    const int gemmBlocks = (NN + BM - 1) / BM;      // 782
    const int aggBlocks  = (NN + 3) / 4;            // 25000

    // ---- layer 1: h = x@W1 ; out = aggregate(h)        (b1 deferred to gemm2)
    k_gemm<<<gemmBlocks, TB, 0, stream>>>(x, W1, nullptr, h, NN);
    k_aggregate<<<aggBlocks, TB, 0, stream>>>(h, csr_src, csr_norm, rowptr, nullptr, out, NN);

    // ---- layer 2: h = relu(out+b1)@W2 ; out = aggregate(h)   (b2 deferred)
    k_gemm<<<gemmBlocks, TB, 0, stream>>>(out, W2, b1, h, NN);
    k_aggregate<<<aggBlocks, TB, 0, stream>>>(h, csr_src, csr_norm, rowptr, nullptr, out, NN);

    // ---- layer 3: h = relu(out+b2)@W3 ; out = aggregate(h) + b3
    k_gemm<<<gemmBlocks, TB, 0, stream>>>(out, W3, b2, h, NN);
    k_aggregate<<<aggBlocks, TB, 0, stream>>>(h, csr_src, csr_norm, rowptr, b3, out, NN);
}

// Round 3
// 407.120 us; speedup vs baseline: 4.2723x; 1.1246x over previous
//
#include <hip/hip_runtime.h>
#include <cstddef>

#define NN 100000
#define NE 600000
#define HID 128

// ---------------------------------------------------------------- degree (int)
__global__ void k_degi(const int* __restrict__ col, int* __restrict__ degi, int E) {
    int e = blockIdx.x * blockDim.x + threadIdx.x;
    if (e < E) atomicAdd(&degi[col[e]], 1);
}

__global__ void k_dinv(const int* __restrict__ degi, float* __restrict__ dinv, int N) {
    int i = blockIdx.x * blockDim.x + threadIdx.x;
    if (i < N) {
        int d = degi[i];
        dinv[i] = d > 0 ? rsqrtf((float)d) : 0.0f;
    }
}

// ---------------------------------------------------------------- prefix scan
__global__ void k_blocksum(const int* __restrict__ degi, int* __restrict__ bsum, int N) {
    __shared__ int sh[256];
    int i = blockIdx.x * 256 + threadIdx.x;
    sh[threadIdx.x] = i < N ? degi[i] : 0;
    __syncthreads();
    for (int s = 128; s > 0; s >>= 1) {
        if (threadIdx.x < s) sh[threadIdx.x] += sh[threadIdx.x + s];
        __syncthreads();
    }
    if (threadIdx.x == 0) bsum[blockIdx.x] = sh[0];
}

// one block, Hillis-Steele over up to 512 block sums -> exclusive
__global__ void k_scan_bsum(int* __restrict__ bsum, int nb) {
    __shared__ int sh[512];
    int tid = threadIdx.x;
    int v = (tid < nb) ? bsum[tid] : 0;
    sh[tid] = v;
    __syncthreads();
    #pragma unroll
    for (int s = 1; s < 512; s <<= 1) {
        int t = (tid >= s) ? sh[tid - s] : 0;
        __syncthreads();
        sh[tid] += t;
        __syncthreads();
    }
    if (tid < nb) bsum[tid] = sh[tid] - v;   // exclusive
}

__global__ void k_scan_apply(const int* __restrict__ degi, const int* __restrict__ bsum,
                             int* __restrict__ rowptr, int* __restrict__ cursor, int N) {
    __shared__ int sh[256];
    int i = blockIdx.x * 256 + threadIdx.x;
    int v = (i < N) ? degi[i] : 0;
    sh[threadIdx.x] = v;
    __syncthreads();
    #pragma unroll
    for (int s = 1; s < 256; s <<= 1) {
        int t = (threadIdx.x >= s) ? sh[threadIdx.x - s] : 0;
        __syncthreads();
        sh[threadIdx.x] += t;
        __syncthreads();
    }
    if (i < N) {
        int excl = bsum[blockIdx.x] + sh[threadIdx.x] - v;
        rowptr[i] = excl;
        cursor[i] = excl;
        if (i == N - 1) rowptr[N] = bsum[blockIdx.x] + sh[threadIdx.x];
    }
}

__global__ void k_fill_csr(const int* __restrict__ row, const int* __restrict__ col,
                           int* __restrict__ cursor, int* __restrict__ csr_src, int E) {
    int e = blockIdx.x * blockDim.x + threadIdx.x;
    if (e >= E) return;
    int r = row[e], c = col[e];
    int pos = atomicAdd(&cursor[c], 1);
    csr_src[pos] = r;
}

// ---------------------------------------------------------------- GEMM
// H[r] = dinv[r] * (act(A[r]) @ W) ; act(x) = bias ? relu(x + bias) : x
// 128x128 tile, 256 threads, 8x8/thread; thread cols = {cg*4..+3} u {64+cg*4..+3}
constexpr int BM = 128;
constexpr int KC = 32;
constexpr int XS = 132;

__global__ __launch_bounds__(256, 4) void k_gemm(
    const float* __restrict__ A, const float* __restrict__ W,
    const float* __restrict__ bias, const float* __restrict__ dinv,
    float* __restrict__ H, int nrows)
{
    __shared__ float ws[KC][HID];    // 16 KB
    __shared__ float xsT[KC][XS];    // 16.9 KB
    const int tid  = threadIdx.x;
    const int row0 = blockIdx.x * BM;
    const int rg   = tid >> 4;   // 0..15 (8 rows each)
    const int cg   = tid & 15;   // 0..15 (2x4 cols)

    float acc[8][8];
    #pragma unroll
    for (int i = 0; i < 8; ++i)
        #pragma unroll
        for (int j = 0; j < 8; ++j) acc[i][j] = 0.0f;

    for (int kc = 0; kc < HID; kc += KC) {
        __syncthreads();
        // stage W chunk: 32x128 = 1024 f4, 4/thread, coalesced
        #pragma unroll
        for (int i = 0; i < 4; ++i) {
            int j = tid + i * 256;
            int k = j >> 5, c4 = j & 31;
            float4 v = ((const float4*)(W + (size_t)(kc + k) * HID))[c4];
            *(float4*)&ws[k][c4 * 4] = v;
        }
        // stage A chunk transposed (fused bias+relu of previous layer)
        #pragma unroll
        for (int i = 0; i < 4; ++i) {
            int j = tid + i * 256;
            int r = j >> 3, kq = j & 7;
            int gr = row0 + r; if (gr >= nrows) gr = nrows - 1;
            float4 v = ((const float4*)(A + (size_t)gr * HID + kc))[kq];
            if (bias) {
                int kb = kc + kq * 4;
                v.x = fmaxf(v.x + bias[kb + 0], 0.0f);
                v.y = fmaxf(v.y + bias[kb + 1], 0.0f);
                v.z = fmaxf(v.z + bias[kb + 2], 0.0f);
                v.w = fmaxf(v.w + bias[kb + 3], 0.0f);
            }
            xsT[kq * 4 + 0][r] = v.x;
            xsT[kq * 4 + 1][r] = v.y;
            xsT[kq * 4 + 2][r] = v.z;
            xsT[kq * 4 + 3][r] = v.w;
        }
        __syncthreads();
        #pragma unroll 4
        for (int k = 0; k < KC; ++k) {
            float xv[8], wv[8];
            *(float4*)&xv[0] = *(const float4*)&xsT[k][rg * 8];
            *(float4*)&xv[4] = *(const float4*)&xsT[k][rg * 8 + 4];
            *(float4*)&wv[0] = *(const float4*)&ws[k][cg * 4];        // banks: free
            *(float4*)&wv[4] = *(const float4*)&ws[k][64 + cg * 4];   // banks: free
            #pragma unroll
            for (int i = 0; i < 8; ++i)
                #pragma unroll
                for (int jj = 0; jj < 8; ++jj)
                    acc[i][jj] = fmaf(xv[i], wv[jj], acc[i][jj]);
        }
    }
    #pragma unroll
    for (int i = 0; i < 8; ++i) {
        int r = row0 + rg * 8 + i;
        if (r < nrows) {
            float s = dinv[r];
            float4 o0 = make_float4(acc[i][0] * s, acc[i][1] * s, acc[i][2] * s, acc[i][3] * s);
            float4 o1 = make_float4(acc[i][4] * s, acc[i][5] * s, acc[i][6] * s, acc[i][7] * s);
            *(float4*)(H + (size_t)r * HID + cg * 4)      = o0;
            *(float4*)(H + (size_t)r * HID + 64 + cg * 4) = o1;
        }
    }
}

// ---------------------------------------------------------------- aggregate (CSR gather)
// hs rows are pre-scaled by dinv[src]; out[c] = dinv[c] * sum(hs[src]) (+bias)
__global__ __launch_bounds__(256) void k_aggregate(
    const float* __restrict__ hs, const int* __restrict__ csr_src,
    const int* __restrict__ rowptr, const float* __restrict__ dinv,
    const float* __restrict__ bias, float* __restrict__ agg, int N)
{
    int node = blockIdx.x * 4 + (threadIdx.x >> 6);
    if (node >= N) return;
    int lane = threadIdx.x & 63;
    int beg = rowptr[node], end = rowptr[node + 1];
    float accx = 0.0f, accy = 0.0f;
    int i = beg;
    for (; i + 1 < end; i += 2) {
        int s0 = csr_src[i], s1 = csr_src[i + 1];
        float2 v0 = *(const float2*)(hs + (size_t)s0 * HID + lane * 2);
        float2 v1 = *(const float2*)(hs + (size_t)s1 * HID + lane * 2);
        accx += v0.x + v1.x; accy += v0.y + v1.y;
    }
    if (i < end) {
        int s0 = csr_src[i];
        float2 v0 = *(const float2*)(hs + (size_t)s0 * HID + lane * 2);
        accx += v0.x; accy += v0.y;
    }
    float s = dinv[node];
    accx *= s; accy *= s;
    if (bias) {
        float2 bv = *(const float2*)(bias + lane * 2);
        accx += bv.x; accy += bv.y;
    }
    *(float2*)(agg + (size_t)node * HID + lane * 2) = make_float2(accx, accy);
}

// ---------------------------------------------------------------- launch
extern "C" void kernel_launch(void* const* d_in, const int* in_sizes, int n_in,
                              void* d_out, int out_size, void* d_ws, size_t ws_size,
                              hipStream_t stream)
{
    const float* x  = (const float*)d_in[0];
    const float* W1 = (const float*)d_in[1];
    const float* b1 = (const float*)d_in[2];
    const float* W2 = (const float*)d_in[3];
    const float* b2 = (const float*)d_in[4];
    const float* W3 = (const float*)d_in[5];
    const float* b3 = (const float*)d_in[6];
    const int*   ei = (const int*)d_in[7];
    const int* row  = ei;            // edge_index[0] (sources)
    const int* colv = ei + NE;       // edge_index[1] (targets)
    float* out = (float*)d_out;

    float* h        = (float*)d_ws;                 // NN*HID floats (51.2 MB)
    int*   degi     = (int*)(h + (size_t)NN * HID); // NN
    float* dinv     = (float*)(degi + NN);          // NN
    int*   rowptr   = (int*)(dinv + NN);            // NN+1
    int*   cursor   = rowptr + NN + 1;              // NN
    int*   bsum     = cursor + NN;                  // <=512
    int*   csr_src  = bsum + 512;                   // NE

    const int TB = 256;
    const int nScanBlocks = (NN + 255) / 256;       // 391

    // ---- CSR build
    hipMemsetAsync(degi, 0, NN * sizeof(int), stream);
    k_degi      <<<(NE + TB - 1) / TB, TB, 0, stream>>>(colv, degi, NE);
    k_dinv      <<<(NN + TB - 1) / TB, TB, 0, stream>>>(degi, dinv, NN);
    k_blocksum  <<<nScanBlocks, 256, 0, stream>>>(degi, bsum, NN);
    k_scan_bsum <<<1, 512, 0, stream>>>(bsum, nScanBlocks);
    k_scan_apply<<<nScanBlocks, 256, 0, stream>>>(degi, bsum, rowptr, cursor, NN);
    k_fill_csr  <<<(NE + TB - 1) / TB, TB, 0, stream>>>(row, colv, cursor, csr_src, NE);

    const int gemmBlocks = (NN + BM - 1) / BM;      // 782
    const int aggBlocks  = (NN + 3) / 4;            // 25000

    // ---- layer 1
    k_gemm<<<gemmBlocks, TB, 0, stream>>>(x, W1, nullptr, dinv, h, NN);
    k_aggregate<<<aggBlocks, TB, 0, stream>>>(h, csr_src, rowptr, dinv, nullptr, out, NN);
    // ---- layer 2
    k_gemm<<<gemmBlocks, TB, 0, stream>>>(out, W2, b1, dinv, h, NN);
    k_aggregate<<<aggBlocks, TB, 0, stream>>>(h, csr_src, rowptr, dinv, nullptr, out, NN);
    // ---- layer 3
    k_gemm<<<gemmBlocks, TB, 0, stream>>>(out, W3, b2, dinv, h, NN);
    k_aggregate<<<aggBlocks, TB, 0, stream>>>(h, csr_src, rowptr, dinv, b3, out, NN);
}

// Round 4
// 289.883 us; speedup vs baseline: 6.0002x; 1.4044x over previous
//
#include <hip/hip_runtime.h>
#include <cstddef>

#define NN 100000
#define NE 600000
#define HID 128

typedef _Float16 half8 __attribute__((ext_vector_type(8)));
typedef _Float16 half2t __attribute__((ext_vector_type(2)));
typedef float f32x4 __attribute__((ext_vector_type(4)));

union H8 { _Float16 h[8]; uint4 u; half8 v; };

// ---------------------------------------------------------------- degree (int)
__global__ void k_degi(const int* __restrict__ col, int* __restrict__ degi, int E) {
    int e = blockIdx.x * blockDim.x + threadIdx.x;
    if (e < E) atomicAdd(&degi[col[e]], 1);
}

__global__ void k_dinv(const int* __restrict__ degi, float* __restrict__ dinv, int N) {
    int i = blockIdx.x * blockDim.x + threadIdx.x;
    if (i < N) {
        int d = degi[i];
        dinv[i] = d > 0 ? rsqrtf((float)d) : 0.0f;
    }
}

// ---------------------------------------------------------------- W -> WT f16
// one block per (layer,k): thread c reads W[k][c] coalesced, writes WT[c][k]
__global__ void k_wprep(const float* __restrict__ W1, const float* __restrict__ W2,
                        const float* __restrict__ W3, _Float16* __restrict__ wt) {
    int b = blockIdx.x;            // 0..383
    int layer = b >> 7, k = b & 127;
    const float* W = layer == 0 ? W1 : (layer == 1 ? W2 : W3);
    int c = threadIdx.x;           // 0..127
    wt[((size_t)layer << 14) + c * 128 + k] = (_Float16)W[k * 128 + c];
}

// ---------------------------------------------------------------- prefix scan
__global__ void k_blocksum(const int* __restrict__ degi, int* __restrict__ bsum, int N) {
    __shared__ int sh[256];
    int i = blockIdx.x * 256 + threadIdx.x;
    sh[threadIdx.x] = i < N ? degi[i] : 0;
    __syncthreads();
    for (int s = 128; s > 0; s >>= 1) {
        if (threadIdx.x < s) sh[threadIdx.x] += sh[threadIdx.x + s];
        __syncthreads();
    }
    if (threadIdx.x == 0) bsum[blockIdx.x] = sh[0];
}

__global__ void k_scan_bsum(int* __restrict__ bsum, int nb) {
    __shared__ int sh[512];
    int tid = threadIdx.x;
    int v = (tid < nb) ? bsum[tid] : 0;
    sh[tid] = v;
    __syncthreads();
    #pragma unroll
    for (int s = 1; s < 512; s <<= 1) {
        int t = (tid >= s) ? sh[tid - s] : 0;
        __syncthreads();
        sh[tid] += t;
        __syncthreads();
    }
    if (tid < nb) bsum[tid] = sh[tid] - v;   // exclusive
}

__global__ void k_scan_apply(const int* __restrict__ degi, const int* __restrict__ bsum,
                             int* __restrict__ rowptr, int* __restrict__ cursor, int N) {
    __shared__ int sh[256];
    int i = blockIdx.x * 256 + threadIdx.x;
    int v = (i < N) ? degi[i] : 0;
    sh[threadIdx.x] = v;
    __syncthreads();
    #pragma unroll
    for (int s = 1; s < 256; s <<= 1) {
        int t = (threadIdx.x >= s) ? sh[threadIdx.x - s] : 0;
        __syncthreads();
        sh[threadIdx.x] += t;
        __syncthreads();
    }
    if (i < N) {
        int excl = bsum[blockIdx.x] + sh[threadIdx.x] - v;
        rowptr[i] = excl;
        cursor[i] = excl;
        if (i == N - 1) rowptr[N] = bsum[blockIdx.x] + sh[threadIdx.x];
    }
}

__global__ void k_fill_csr(const int* __restrict__ row, const int* __restrict__ col,
                           int* __restrict__ cursor, int* __restrict__ csr_src, int E) {
    int e = blockIdx.x * blockDim.x + threadIdx.x;
    if (e >= E) return;
    int r = row[e], c = col[e];
    int pos = atomicAdd(&cursor[c], 1);
    csr_src[pos] = r;
}

// ---------------------------------------------------------------- MFMA GEMM
// H[r] (f16) = dinv[r] * (act(A[r]) @ W) ; act = bias ? relu(.+bias) : id
// block: 256 thr = 4 waves; tile 128x128xK128; wave -> 64x64 quadrant.
// LDS f16 tiles with XOR swizzle: idx = row*128 + (col ^ ((row&7)<<3))
template <typename TA>
__global__ __launch_bounds__(256, 2) void k_gemm(
    const TA* __restrict__ A, const _Float16* __restrict__ WT,
    const float* __restrict__ bias, const float* __restrict__ dinv,
    _Float16* __restrict__ H, int nrows)
{
    __shared__ _Float16 asl[128 * 128];   // 32 KB
    __shared__ _Float16 wsl[128 * 128];   // 32 KB
    const int tid  = threadIdx.x;
    const int lane = tid & 63;
    const int w    = tid >> 6;
    const int wm   = w >> 1, wn = w & 1;
    const int ln15 = lane & 15;
    const int hi   = lane >> 4;           // 0..3
    const int row0 = blockIdx.x * 128;

    // ---- stage WT (f16, linear->swizzled), 16B per thread per iter
    #pragma unroll
    for (int i = 0; i < 8; ++i) {
        int g = i * 256 + tid;
        int c = g >> 4, k8 = (g & 15) << 3;
        uint4 wv = *(const uint4*)(WT + c * 128 + k8);
        *(uint4*)&wsl[c * 128 + (k8 ^ ((c & 7) << 3))] = wv;
    }
    // ---- stage A (convert -> f16, fused bias+relu of previous layer)
    #pragma unroll
    for (int i = 0; i < 8; ++i) {
        int g = i * 256 + tid;
        int r = g >> 4, c8 = (g & 15) << 3;
        int gr = row0 + r; if (gr >= nrows) gr = nrows - 1;
        float vf[8];
        if constexpr (sizeof(TA) == 4) {
            const float4* src = (const float4*)(A + (size_t)gr * HID + c8);
            float4 v0 = src[0], v1 = src[1];
            vf[0] = v0.x; vf[1] = v0.y; vf[2] = v0.z; vf[3] = v0.w;
            vf[4] = v1.x; vf[5] = v1.y; vf[6] = v1.z; vf[7] = v1.w;
        } else {
            H8 hv; hv.u = *(const uint4*)(A + (size_t)gr * HID + c8);
            #pragma unroll
            for (int j = 0; j < 8; ++j) vf[j] = (float)hv.h[j];
        }
        if (bias) {
            #pragma unroll
            for (int j = 0; j < 8; ++j) vf[j] = fmaxf(vf[j] + bias[c8 + j], 0.0f);
        }
        H8 o;
        #pragma unroll
        for (int j = 0; j < 8; ++j) o.h[j] = (_Float16)vf[j];
        *(uint4*)&asl[r * 128 + (c8 ^ ((r & 7) << 3))] = o.u;
    }
    __syncthreads();

    f32x4 acc[4][4];
    #pragma unroll
    for (int i = 0; i < 4; ++i)
        #pragma unroll
        for (int j = 0; j < 4; ++j) {
            acc[i][j][0] = 0.0f; acc[i][j][1] = 0.0f;
            acc[i][j][2] = 0.0f; acc[i][j][3] = 0.0f;
        }

    #pragma unroll
    for (int ks = 0; ks < 4; ++ks) {
        const int k0 = ks * 32 + hi * 8;
        half8 a[4], b[4];
        #pragma unroll
        for (int i = 0; i < 4; ++i) {
            int ra = wm * 64 + i * 16 + ln15;
            a[i] = *(const half8*)&asl[ra * 128 + (k0 ^ ((ra & 7) << 3))];
            int cb = wn * 64 + i * 16 + ln15;
            b[i] = *(const half8*)&wsl[cb * 128 + (k0 ^ ((cb & 7) << 3))];
        }
        #pragma unroll
        for (int i = 0; i < 4; ++i)
            #pragma unroll
            for (int j = 0; j < 4; ++j)
                acc[i][j] = __builtin_amdgcn_mfma_f32_16x16x32_f16(a[i], b[j], acc[i][j], 0, 0, 0);
    }

    // ---- epilogue: D[row=(hi*4+q)][col=ln15] per fragment; scale by dinv[r]
    #pragma unroll
    for (int i = 0; i < 4; ++i) {
        #pragma unroll
        for (int q = 0; q < 4; ++q) {
            int r = row0 + wm * 64 + i * 16 + hi * 4 + q;
            if (r < nrows) {
                float s = dinv[r];
                #pragma unroll
                for (int j = 0; j < 4; ++j) {
                    H[(size_t)r * HID + wn * 64 + j * 16 + ln15] =
                        (_Float16)(acc[i][j][q] * s);
                }
            }
        }
    }
}

// ---------------------------------------------------------------- aggregate
// hs rows pre-scaled by dinv[src]; out[c] = dinv[c]*sum(hs[src]) (+b3 if FINAL)
template <bool FINAL>
__global__ __launch_bounds__(256) void k_aggregate(
    const _Float16* __restrict__ hs, const int* __restrict__ csr_src,
    const int* __restrict__ rowptr, const float* __restrict__ dinv,
    const float* __restrict__ bias, void* __restrict__ aggv, int N)
{
    int node = blockIdx.x * 4 + (threadIdx.x >> 6);
    if (node >= N) return;
    int lane = threadIdx.x & 63;
    int beg = rowptr[node], end = rowptr[node + 1];
    float accx = 0.0f, accy = 0.0f;
    int i = beg;
    for (; i + 1 < end; i += 2) {
        int s0 = csr_src[i], s1 = csr_src[i + 1];
        half2t v0 = *(const half2t*)(hs + (size_t)s0 * HID + lane * 2);
        half2t v1 = *(const half2t*)(hs + (size_t)s1 * HID + lane * 2);
        accx += (float)v0[0] + (float)v1[0];
        accy += (float)v0[1] + (float)v1[1];
    }
    if (i < end) {
        int s0 = csr_src[i];
        half2t v0 = *(const half2t*)(hs + (size_t)s0 * HID + lane * 2);
        accx += (float)v0[0]; accy += (float)v0[1];
    }
    float s = dinv[node];
    accx *= s; accy *= s;
    if constexpr (FINAL) {
        float2 bv = *(const float2*)(bias + lane * 2);
        float2* dst = (float2*)((float*)aggv + (size_t)node * HID + lane * 2);
        *dst = make_float2(accx + bv.x, accy + bv.y);
    } else {
        half2t o; o[0] = (_Float16)accx; o[1] = (_Float16)accy;
        *(half2t*)((_Float16*)aggv + (size_t)node * HID + lane * 2) = o;
    }
}

// ---------------------------------------------------------------- launch
extern "C" void kernel_launch(void* const* d_in, const int* in_sizes, int n_in,
                              void* d_out, int out_size, void* d_ws, size_t ws_size,
                              hipStream_t stream)
{
    const float* x  = (const float*)d_in[0];
    const float* W1 = (const float*)d_in[1];
    const float* b1 = (const float*)d_in[2];
    const float* W2 = (const float*)d_in[3];
    const float* b2 = (const float*)d_in[4];
    const float* W3 = (const float*)d_in[5];
    const float* b3 = (const float*)d_in[6];
    const int*   ei = (const int*)d_in[7];
    const int* row  = ei;            // sources
    const int* colv = ei + NE;       // targets
    float* out = (float*)d_out;

    _Float16* h16 = (_Float16*)d_ws;                  // NN*HID  (25.6 MB)
    _Float16* a16 = h16 + (size_t)NN * HID;           // NN*HID  (25.6 MB)
    _Float16* wt  = a16 + (size_t)NN * HID;           // 3*128*128
    int*   degi    = (int*)(wt + 3 * 128 * 128);      // NN
    float* dinv    = (float*)(degi + NN);             // NN
    int*   rowptr  = (int*)(dinv + NN);               // NN+1
    int*   cursor  = rowptr + NN + 1;                 // NN
    int*   bsum    = cursor + NN;                     // 512
    int*   csr_src = bsum + 512;                      // NE

    const int TB = 256;
    const int nScanBlocks = (NN + 255) / 256;         // 391

    // ---- weight prep + CSR build
    k_wprep<<<384, 128, 0, stream>>>(W1, W2, W3, wt);
    hipMemsetAsync(degi, 0, NN * sizeof(int), stream);
    k_degi      <<<(NE + TB - 1) / TB, TB, 0, stream>>>(colv, degi, NE);
    k_dinv      <<<(NN + TB - 1) / TB, TB, 0, stream>>>(degi, dinv, NN);
    k_blocksum  <<<nScanBlocks, 256, 0, stream>>>(degi, bsum, NN);
    k_scan_bsum <<<1, 512, 0, stream>>>(bsum, nScanBlocks);
    k_scan_apply<<<nScanBlocks, 256, 0, stream>>>(degi, bsum, rowptr, cursor, NN);
    k_fill_csr  <<<(NE + TB - 1) / TB, TB, 0, stream>>>(row, colv, cursor, csr_src, NE);

    const int gemmBlocks = (NN + 127) / 128;          // 782
    const int aggBlocks  = (NN + 3) / 4;              // 25000

    // ---- layer 1: h16 = dinv*(x@W1) ; a16 = aggregate(h16)
    k_gemm<float><<<gemmBlocks, TB, 0, stream>>>(x, wt, nullptr, dinv, h16, NN);
    k_aggregate<false><<<aggBlocks, TB, 0, stream>>>(h16, csr_src, rowptr, dinv, nullptr, a16, NN);
    // ---- layer 2: h16 = dinv*(relu(a16+b1)@W2) ; a16 = aggregate(h16)
    k_gemm<_Float16><<<gemmBlocks, TB, 0, stream>>>(a16, wt + (1 << 14), b1, dinv, h16, NN);
    k_aggregate<false><<<aggBlocks, TB, 0, stream>>>(h16, csr_src, rowptr, dinv, nullptr, a16, NN);
    // ---- layer 3: h16 = dinv*(relu(a16+b2)@W3) ; out = aggregate(h16) + b3
    k_gemm<_Float16><<<gemmBlocks, TB, 0, stream>>>(a16, wt + (2 << 14), b2, dinv, h16, NN);
    k_aggregate<true><<<aggBlocks, TB, 0, stream>>>(h16, csr_src, rowptr, dinv, b3, out, NN);
}

// Round 5
// 255.979 us; speedup vs baseline: 6.7949x; 1.1325x over previous
//
#include <hip/hip_runtime.h>
#include <cstddef>

#define NN 100000
#define NE 600000
#define HID 128

typedef _Float16 half8 __attribute__((ext_vector_type(8)));
typedef float f32x4 __attribute__((ext_vector_type(4)));

union H8 { _Float16 h[8]; uint4 u; half8 v; };

// ---------------------------------------------------------------- degree (int)
__global__ void k_degi(const int* __restrict__ col, int* __restrict__ degi, int E) {
    int e = blockIdx.x * blockDim.x + threadIdx.x;
    if (e < E) atomicAdd(&degi[col[e]], 1);
}

// ---------------------------------------------------------------- W -> WT f16
__global__ void k_wprep(const float* __restrict__ W1, const float* __restrict__ W2,
                        const float* __restrict__ W3, _Float16* __restrict__ wt) {
    int b = blockIdx.x;            // 0..383
    int layer = b >> 7, k = b & 127;
    const float* W = layer == 0 ? W1 : (layer == 1 ? W2 : W3);
    int c = threadIdx.x;           // 0..127
    wt[((size_t)layer << 14) + c * 128 + k] = (_Float16)W[k * 128 + c];
}

// ---------------------------------------------------------------- prefix scan
// block reduce degi -> bsum, and write dinv (fused)
__global__ void k_blocksum(const int* __restrict__ degi, float* __restrict__ dinv,
                           int* __restrict__ bsum, int N) {
    __shared__ int sh[256];
    int i = blockIdx.x * 256 + threadIdx.x;
    int v = i < N ? degi[i] : 0;
    if (i < N) dinv[i] = v > 0 ? rsqrtf((float)v) : 0.0f;
    sh[threadIdx.x] = v;
    __syncthreads();
    for (int s = 128; s > 0; s >>= 1) {
        if (threadIdx.x < s) sh[threadIdx.x] += sh[threadIdx.x + s];
        __syncthreads();
    }
    if (threadIdx.x == 0) bsum[blockIdx.x] = sh[0];
}

__global__ void k_scan_bsum(int* __restrict__ bsum, int nb) {
    __shared__ int sh[512];
    int tid = threadIdx.x;
    int v = (tid < nb) ? bsum[tid] : 0;
    sh[tid] = v;
    __syncthreads();
    #pragma unroll
    for (int s = 1; s < 512; s <<= 1) {
        int t = (tid >= s) ? sh[tid - s] : 0;
        __syncthreads();
        sh[tid] += t;
        __syncthreads();
    }
    if (tid < nb) bsum[tid] = sh[tid] - v;   // exclusive
}

__global__ void k_scan_apply(const int* __restrict__ degi, const int* __restrict__ bsum,
                             int* __restrict__ rowptr, int* __restrict__ cursor, int N) {
    __shared__ int sh[256];
    int i = blockIdx.x * 256 + threadIdx.x;
    int v = (i < N) ? degi[i] : 0;
    sh[threadIdx.x] = v;
    __syncthreads();
    #pragma unroll
    for (int s = 1; s < 256; s <<= 1) {
        int t = (threadIdx.x >= s) ? sh[threadIdx.x - s] : 0;
        __syncthreads();
        sh[threadIdx.x] += t;
        __syncthreads();
    }
    if (i < N) {
        int excl = bsum[blockIdx.x] + sh[threadIdx.x] - v;
        rowptr[i] = excl;
        cursor[i] = excl;
        if (i == N - 1) rowptr[N] = bsum[blockIdx.x] + sh[threadIdx.x];
    }
}

__global__ void k_fill_csr(const int* __restrict__ row, const int* __restrict__ col,
                           int* __restrict__ cursor, int* __restrict__ csr_src, int E) {
    int e = blockIdx.x * blockDim.x + threadIdx.x;
    if (e >= E) return;
    int r = row[e], c = col[e];
    int pos = atomicAdd(&cursor[c], 1);
    csr_src[pos] = r;
}

// ---------------------------------------------------------------- MFMA GEMM
// H[r] (f16) = dinv[r] * (A[r] @ W)   (A pre-activated by aggregate)
template <typename TA>
__global__ __launch_bounds__(256, 2) void k_gemm(
    const TA* __restrict__ A, const _Float16* __restrict__ WT,
    const float* __restrict__ dinv, _Float16* __restrict__ H, int nrows)
{
    __shared__ _Float16 asl[128 * 128];   // 32 KB
    __shared__ _Float16 wsl[128 * 128];   // 32 KB
    const int tid  = threadIdx.x;
    const int lane = tid & 63;
    const int w    = tid >> 6;
    const int wm   = w >> 1, wn = w & 1;
    const int ln15 = lane & 15;
    const int hi   = lane >> 4;           // 0..3
    const int row0 = blockIdx.x * 128;

    #pragma unroll
    for (int i = 0; i < 8; ++i) {
        int g = i * 256 + tid;
        int c = g >> 4, k8 = (g & 15) << 3;
        uint4 wv = *(const uint4*)(WT + c * 128 + k8);
        *(uint4*)&wsl[c * 128 + (k8 ^ ((c & 7) << 3))] = wv;
    }
    #pragma unroll
    for (int i = 0; i < 8; ++i) {
        int g = i * 256 + tid;
        int r = g >> 4, c8 = (g & 15) << 3;
        int gr = row0 + r; if (gr >= nrows) gr = nrows - 1;
        if constexpr (sizeof(TA) == 4) {
            const float4* src = (const float4*)(A + (size_t)gr * HID + c8);
            float4 v0 = src[0], v1 = src[1];
            H8 o;
            o.h[0] = (_Float16)v0.x; o.h[1] = (_Float16)v0.y;
            o.h[2] = (_Float16)v0.z; o.h[3] = (_Float16)v0.w;
            o.h[4] = (_Float16)v1.x; o.h[5] = (_Float16)v1.y;
            o.h[6] = (_Float16)v1.z; o.h[7] = (_Float16)v1.w;
            *(uint4*)&asl[r * 128 + (c8 ^ ((r & 7) << 3))] = o.u;
        } else {
            uint4 u = *(const uint4*)(A + (size_t)gr * HID + c8);
            *(uint4*)&asl[r * 128 + (c8 ^ ((r & 7) << 3))] = u;
        }
    }
    __syncthreads();

    f32x4 acc[4][4];
    #pragma unroll
    for (int i = 0; i < 4; ++i)
        #pragma unroll
        for (int j = 0; j < 4; ++j) {
            acc[i][j][0] = 0.0f; acc[i][j][1] = 0.0f;
            acc[i][j][2] = 0.0f; acc[i][j][3] = 0.0f;
        }

    #pragma unroll
    for (int ks = 0; ks < 4; ++ks) {
        const int k0 = ks * 32 + hi * 8;
        half8 a[4], b[4];
        #pragma unroll
        for (int i = 0; i < 4; ++i) {
            int ra = wm * 64 + i * 16 + ln15;
            a[i] = *(const half8*)&asl[ra * 128 + (k0 ^ ((ra & 7) << 3))];
            int cb = wn * 64 + i * 16 + ln15;
            b[i] = *(const half8*)&wsl[cb * 128 + (k0 ^ ((cb & 7) << 3))];
        }
        #pragma unroll
        for (int i = 0; i < 4; ++i)
            #pragma unroll
            for (int j = 0; j < 4; ++j)
                acc[i][j] = __builtin_amdgcn_mfma_f32_16x16x32_f16(a[i], b[j], acc[i][j], 0, 0, 0);
    }

    #pragma unroll
    for (int i = 0; i < 4; ++i) {
        #pragma unroll
        for (int q = 0; q < 4; ++q) {
            int r = row0 + wm * 64 + i * 16 + hi * 4 + q;
            if (r < nrows) {
                float s = dinv[r];
                #pragma unroll
                for (int j = 0; j < 4; ++j) {
                    H[(size_t)r * HID + wn * 64 + j * 16 + ln15] =
                        (_Float16)(acc[i][j][q] * s);
                }
            }
        }
    }
}

// ---------------------------------------------------------------- aggregate
// one WAVE per node; lane = eslot*16 + fg; each round gathers 4 source rows.
// MODE 0: a16[node] = relu(dinv*acc + bias)  (f16)
// MODE 1: out[node] = dinv*acc + bias        (f32)
template <int MODE>
__global__ __launch_bounds__(256) void k_aggregate(
    const _Float16* __restrict__ hs, const int* __restrict__ csr_src,
    const int* __restrict__ rowptr, const float* __restrict__ dinv,
    const float* __restrict__ bias, void* __restrict__ aggv, int N)
{
    int node = blockIdx.x * 4 + (threadIdx.x >> 6);
    if (node >= N) return;
    int lane  = threadIdx.x & 63;
    int eslot = lane >> 4;          // 0..3  edge slot
    int fg    = lane & 15;          // feature group: features fg*8 .. fg*8+7
    int beg = rowptr[node], end = rowptr[node + 1];

    float accf[8];
    #pragma unroll
    for (int j = 0; j < 8; ++j) accf[j] = 0.0f;

    const uint4 z = make_uint4(0, 0, 0, 0);
    int nr = (end - beg + 3) >> 2;      // wave-uniform round count
    int e  = beg + eslot;
    int r  = 0;
    for (; r + 1 < nr; r += 2, e += 8) {
        int s0 = (e     < end) ? csr_src[e]     : -1;
        int s1 = (e + 4 < end) ? csr_src[e + 4] : -1;
        uint4 u0 = (s0 >= 0) ? *(const uint4*)(hs + (size_t)s0 * HID + fg * 8) : z;
        uint4 u1 = (s1 >= 0) ? *(const uint4*)(hs + (size_t)s1 * HID + fg * 8) : z;
        H8 h0; h0.u = u0;
        H8 h1; h1.u = u1;
        #pragma unroll
        for (int j = 0; j < 8; ++j)
            accf[j] += (float)h0.h[j] + (float)h1.h[j];
    }
    if (r < nr) {
        int s0 = (e < end) ? csr_src[e] : -1;
        uint4 u0 = (s0 >= 0) ? *(const uint4*)(hs + (size_t)s0 * HID + fg * 8) : z;
        H8 h0; h0.u = u0;
        #pragma unroll
        for (int j = 0; j < 8; ++j) accf[j] += (float)h0.h[j];
    }

    // fold the 4 edge slots
    #pragma unroll
    for (int j = 0; j < 8; ++j) {
        accf[j] += __shfl_xor(accf[j], 16);
        accf[j] += __shfl_xor(accf[j], 32);
    }

    if (eslot == 0) {
        float s = dinv[node];
        float4 b0 = *(const float4*)(bias + fg * 8);
        float4 b1 = *(const float4*)(bias + fg * 8 + 4);
        float o[8];
        o[0] = accf[0] * s + b0.x; o[1] = accf[1] * s + b0.y;
        o[2] = accf[2] * s + b0.z; o[3] = accf[3] * s + b0.w;
        o[4] = accf[4] * s + b1.x; o[5] = accf[5] * s + b1.y;
        o[6] = accf[6] * s + b1.z; o[7] = accf[7] * s + b1.w;
        if constexpr (MODE == 0) {
            H8 oh;
            #pragma unroll
            for (int j = 0; j < 8; ++j) oh.h[j] = (_Float16)fmaxf(o[j], 0.0f);
            *(uint4*)((_Float16*)aggv + (size_t)node * HID + fg * 8) = oh.u;
        } else {
            float* dst = (float*)aggv + (size_t)node * HID + fg * 8;
            *(float4*)dst       = make_float4(o[0], o[1], o[2], o[3]);
            *(float4*)(dst + 4) = make_float4(o[4], o[5], o[6], o[7]);
        }
    }
}

// ---------------------------------------------------------------- launch
extern "C" void kernel_launch(void* const* d_in, const int* in_sizes, int n_in,
                              void* d_out, int out_size, void* d_ws, size_t ws_size,
                              hipStream_t stream)
{
    const float* x  = (const float*)d_in[0];
    const float* W1 = (const float*)d_in[1];
    const float* b1 = (const float*)d_in[2];
    const float* W2 = (const float*)d_in[3];
    const float* b2 = (const float*)d_in[4];
    const float* W3 = (const float*)d_in[5];
    const float* b3 = (const float*)d_in[6];
    const int*   ei = (const int*)d_in[7];
    const int* row  = ei;            // sources
    const int* colv = ei + NE;       // targets
    float* out = (float*)d_out;

    _Float16* h16 = (_Float16*)d_ws;                  // NN*HID
    _Float16* a16 = h16 + (size_t)NN * HID;           // NN*HID
    _Float16* wt  = a16 + (size_t)NN * HID;           // 3*128*128
    int*   degi    = (int*)(wt + 3 * 128 * 128);      // NN
    float* dinv    = (float*)(degi + NN);             // NN
    int*   rowptr  = (int*)(dinv + NN);               // NN+1
    int*   cursor  = rowptr + NN + 1;                 // NN
    int*   bsum    = cursor + NN;                     // 512
    int*   csr_src = bsum + 512;                      // NE

    const int TB = 256;
    const int nScanBlocks = (NN + 255) / 256;         // 391

    k_wprep<<<384, 128, 0, stream>>>(W1, W2, W3, wt);
    hipMemsetAsync(degi, 0, NN * sizeof(int), stream);
    k_degi      <<<(NE + TB - 1) / TB, TB, 0, stream>>>(colv, degi, NE);
    k_blocksum  <<<nScanBlocks, 256, 0, stream>>>(degi, dinv, bsum, NN);
    k_scan_bsum <<<1, 512, 0, stream>>>(bsum, nScanBlocks);
    k_scan_apply<<<nScanBlocks, 256, 0, stream>>>(degi, bsum, rowptr, cursor, NN);
    k_fill_csr  <<<(NE + TB - 1) / TB, TB, 0, stream>>>(row, colv, cursor, csr_src, NE);

    const int gemmBlocks = (NN + 127) / 128;          // 782
    const int aggBlocks  = (NN + 3) / 4;              // 25000

    // layer 1: h16 = dinv*(x@W1) ; a16 = relu(agg(h16)+b1)
    k_gemm<float><<<gemmBlocks, TB, 0, stream>>>(x, wt, dinv, h16, NN);
    k_aggregate<0><<<aggBlocks, TB, 0, stream>>>(h16, csr_src, rowptr, dinv, b1, a16, NN);
    // layer 2: h16 = dinv*(a16@W2) ; a16 = relu(agg(h16)+b2)
    k_gemm<_Float16><<<gemmBlocks, TB, 0, stream>>>(a16, wt + (1 << 14), dinv, h16, NN);
    k_aggregate<0><<<aggBlocks, TB, 0, stream>>>(h16, csr_src, rowptr, dinv, b2, a16, NN);
    // layer 3: h16 = dinv*(a16@W3) ; out = agg(h16) + b3
    k_gemm<_Float16><<<gemmBlocks, TB, 0, stream>>>(a16, wt + (2 << 14), dinv, h16, NN);
    k_aggregate<1><<<aggBlocks, TB, 0, stream>>>(h16, csr_src, rowptr, dinv, b3, out, NN);
}

// Round 6
// 253.084 us; speedup vs baseline: 6.8726x; 1.0114x over previous
//
#include <hip/hip_runtime.h>
#include <cstddef>

#define NN 100000
#define NE 600000
#define HID 128

typedef _Float16 half8 __attribute__((ext_vector_type(8)));
typedef float f32x4 __attribute__((ext_vector_type(4)));

union H8 { _Float16 h[8]; uint4 u; half8 v; };

// ---------------------------------------------------------------- degree (int)
__global__ void k_degi(const int* __restrict__ col, int* __restrict__ degi, int E) {
    int e = blockIdx.x * blockDim.x + threadIdx.x;
    if (e < E) atomicAdd(&degi[col[e]], 1);
}

// ---------------------------------------------------------------- W -> WT f16
__global__ void k_wprep(const float* __restrict__ W1, const float* __restrict__ W2,
                        const float* __restrict__ W3, _Float16* __restrict__ wt) {
    int b = blockIdx.x;            // 0..383
    int layer = b >> 7, k = b & 127;
    const float* W = layer == 0 ? W1 : (layer == 1 ? W2 : W3);
    int c = threadIdx.x;           // 0..127
    wt[((size_t)layer << 14) + c * 128 + k] = (_Float16)W[k * 128 + c];
}

// ---------------------------------------------------------------- prefix scan
__global__ void k_blocksum(const int* __restrict__ degi, float* __restrict__ dinv,
                           int* __restrict__ bsum, int N) {
    __shared__ int sh[256];
    int i = blockIdx.x * 256 + threadIdx.x;
    int v = i < N ? degi[i] : 0;
    if (i < N) dinv[i] = v > 0 ? rsqrtf((float)v) : 0.0f;
    sh[threadIdx.x] = v;
    __syncthreads();
    for (int s = 128; s > 0; s >>= 1) {
        if (threadIdx.x < s) sh[threadIdx.x] += sh[threadIdx.x + s];
        __syncthreads();
    }
    if (threadIdx.x == 0) bsum[blockIdx.x] = sh[0];
}

__global__ void k_scan_bsum(int* __restrict__ bsum, int nb) {
    __shared__ int sh[512];
    int tid = threadIdx.x;
    int v = (tid < nb) ? bsum[tid] : 0;
    sh[tid] = v;
    __syncthreads();
    #pragma unroll
    for (int s = 1; s < 512; s <<= 1) {
        int t = (tid >= s) ? sh[tid - s] : 0;
        __syncthreads();
        sh[tid] += t;
        __syncthreads();
    }
    if (tid < nb) bsum[tid] = sh[tid] - v;   // exclusive
}

__global__ void k_scan_apply(const int* __restrict__ degi, const int* __restrict__ bsum,
                             int* __restrict__ rowptr, int* __restrict__ cursor, int N) {
    __shared__ int sh[256];
    int i = blockIdx.x * 256 + threadIdx.x;
    int v = (i < N) ? degi[i] : 0;
    sh[threadIdx.x] = v;
    __syncthreads();
    #pragma unroll
    for (int s = 1; s < 256; s <<= 1) {
        int t = (threadIdx.x >= s) ? sh[threadIdx.x - s] : 0;
        __syncthreads();
        sh[threadIdx.x] += t;
        __syncthreads();
    }
    if (i < N) {
        int excl = bsum[blockIdx.x] + sh[threadIdx.x] - v;
        rowptr[i] = excl;
        cursor[i] = excl;
        if (i == N - 1) rowptr[N] = bsum[blockIdx.x] + sh[threadIdx.x];
    }
}

__global__ void k_fill_csr(const int* __restrict__ row, const int* __restrict__ col,
                           int* __restrict__ cursor, int* __restrict__ csr_src, int E) {
    int e = blockIdx.x * blockDim.x + threadIdx.x;
    if (e >= E) return;
    int r = row[e], c = col[e];
    int pos = atomicAdd(&cursor[c], 1);
    csr_src[pos] = r;
}

// ---------------------------------------------------------------- MFMA GEMM
// H[r] (f16) = dinv[r] * (A[r] @ W)   (A pre-activated by aggregate)
template <typename TA>
__global__ __launch_bounds__(256, 2) void k_gemm(
    const TA* __restrict__ A, const _Float16* __restrict__ WT,
    const float* __restrict__ dinv, _Float16* __restrict__ H, int nrows)
{
    __shared__ _Float16 asl[128 * 128];   // 32 KB
    __shared__ _Float16 wsl[128 * 128];   // 32 KB
    const int tid  = threadIdx.x;
    const int lane = tid & 63;
    const int w    = tid >> 6;
    const int wm   = w >> 1, wn = w & 1;
    const int ln15 = lane & 15;
    const int hi   = lane >> 4;           // 0..3
    const int row0 = blockIdx.x * 128;

    #pragma unroll
    for (int i = 0; i < 8; ++i) {
        int g = i * 256 + tid;
        int c = g >> 4, k8 = (g & 15) << 3;
        uint4 wv = *(const uint4*)(WT + c * 128 + k8);
        *(uint4*)&wsl[c * 128 + (k8 ^ ((c & 7) << 3))] = wv;
    }
    #pragma unroll
    for (int i = 0; i < 8; ++i) {
        int g = i * 256 + tid;
        int r = g >> 4, c8 = (g & 15) << 3;
        int gr = row0 + r; if (gr >= nrows) gr = nrows - 1;
        if constexpr (sizeof(TA) == 4) {
            const float4* src = (const float4*)(A + (size_t)gr * HID + c8);
            float4 v0 = src[0], v1 = src[1];
            H8 o;
            o.h[0] = (_Float16)v0.x; o.h[1] = (_Float16)v0.y;
            o.h[2] = (_Float16)v0.z; o.h[3] = (_Float16)v0.w;
            o.h[4] = (_Float16)v1.x; o.h[5] = (_Float16)v1.y;
            o.h[6] = (_Float16)v1.z; o.h[7] = (_Float16)v1.w;
            *(uint4*)&asl[r * 128 + (c8 ^ ((r & 7) << 3))] = o.u;
        } else {
            uint4 u = *(const uint4*)(A + (size_t)gr * HID + c8);
            *(uint4*)&asl[r * 128 + (c8 ^ ((r & 7) << 3))] = u;
        }
    }
    __syncthreads();

    f32x4 acc[4][4];
    #pragma unroll
    for (int i = 0; i < 4; ++i)
        #pragma unroll
        for (int j = 0; j < 4; ++j) {
            acc[i][j][0] = 0.0f; acc[i][j][1] = 0.0f;
            acc[i][j][2] = 0.0f; acc[i][j][3] = 0.0f;
        }

    #pragma unroll
    for (int ks = 0; ks < 4; ++ks) {
        const int k0 = ks * 32 + hi * 8;
        half8 a[4], b[4];
        #pragma unroll
        for (int i = 0; i < 4; ++i) {
            int ra = wm * 64 + i * 16 + ln15;
            a[i] = *(const half8*)&asl[ra * 128 + (k0 ^ ((ra & 7) << 3))];
            int cb = wn * 64 + i * 16 + ln15;
            b[i] = *(const half8*)&wsl[cb * 128 + (k0 ^ ((cb & 7) << 3))];
        }
        #pragma unroll
        for (int i = 0; i < 4; ++i)
            #pragma unroll
            for (int j = 0; j < 4; ++j)
                acc[i][j] = __builtin_amdgcn_mfma_f32_16x16x32_f16(a[i], b[j], acc[i][j], 0, 0, 0);
    }

    #pragma unroll
    for (int i = 0; i < 4; ++i) {
        #pragma unroll
        for (int q = 0; q < 4; ++q) {
            int r = row0 + wm * 64 + i * 16 + hi * 4 + q;
            if (r < nrows) {
                float s = dinv[r];
                #pragma unroll
                for (int j = 0; j < 4; ++j) {
                    H[(size_t)r * HID + wn * 64 + j * 16 + ln15] =
                        (_Float16)(acc[i][j][q] * s);
                }
            }
        }
    }
}

// ---------------------------------------------------------------- aggregate
// one WAVE per node; lane = eslot*16 + fg; each round gathers 4 source rows.
// After the xor-fold ALL lanes hold the full 8-feature sum for group fg;
// lane (es,fg) stores feature pair f0 = fg*8 + es*2 -> 64-lane contiguous store.
// MODE 0: a16[node] = relu(dinv*acc + bias)  (f16)
// MODE 1: out[node] = dinv*acc + bias        (f32)
template <int MODE>
__global__ __launch_bounds__(256) void k_aggregate(
    const _Float16* __restrict__ hs, const int* __restrict__ csr_src,
    const int* __restrict__ rowptr, const float* __restrict__ dinv,
    const float* __restrict__ bias, void* __restrict__ aggv, int N)
{
    int node = blockIdx.x * 4 + (threadIdx.x >> 6);
    if (node >= N) return;
    int lane  = threadIdx.x & 63;
    int es    = lane >> 4;          // 0..3  edge slot
    int fg    = lane & 15;          // feature group: features fg*8 .. fg*8+7
    int beg = rowptr[node], end = rowptr[node + 1];

    float accf[8];
    #pragma unroll
    for (int j = 0; j < 8; ++j) accf[j] = 0.0f;

    const uint4 z = make_uint4(0, 0, 0, 0);
    int nr = (end - beg + 3) >> 2;      // wave-uniform round count
    int e  = beg + es;
    int r  = 0;
    for (; r + 1 < nr; r += 2, e += 8) {
        int s0 = (e     < end) ? csr_src[e]     : -1;
        int s1 = (e + 4 < end) ? csr_src[e + 4] : -1;
        uint4 u0 = (s0 >= 0) ? *(const uint4*)(hs + (size_t)s0 * HID + fg * 8) : z;
        uint4 u1 = (s1 >= 0) ? *(const uint4*)(hs + (size_t)s1 * HID + fg * 8) : z;
        H8 h0; h0.u = u0;
        H8 h1; h1.u = u1;
        #pragma unroll
        for (int j = 0; j < 8; ++j)
            accf[j] += (float)h0.h[j] + (float)h1.h[j];
    }
    if (r < nr) {
        int s0 = (e < end) ? csr_src[e] : -1;
        uint4 u0 = (s0 >= 0) ? *(const uint4*)(hs + (size_t)s0 * HID + fg * 8) : z;
        H8 h0; h0.u = u0;
        #pragma unroll
        for (int j = 0; j < 8; ++j) accf[j] += (float)h0.h[j];
    }

    // fold the 4 edge slots — butterfly leaves full sum in EVERY lane
    #pragma unroll
    for (int j = 0; j < 8; ++j) {
        accf[j] += __shfl_xor(accf[j], 16);
        accf[j] += __shfl_xor(accf[j], 32);
    }

    // lane (es,fg) owns features f0, f0+1 (static ?: select — no dyn indexing)
    float v0 = es < 2 ? (es == 0 ? accf[0] : accf[2])
                      : (es == 2 ? accf[4] : accf[6]);
    float v1 = es < 2 ? (es == 0 ? accf[1] : accf[3])
                      : (es == 2 ? accf[5] : accf[7]);
    int f0 = fg * 8 + es * 2;
    float s = dinv[node];
    float2 bv = *(const float2*)(bias + f0);
    v0 = v0 * s + bv.x;
    v1 = v1 * s + bv.y;
    if constexpr (MODE == 0) {
        union { _Float16 h[2]; unsigned u; } o;
        o.h[0] = (_Float16)fmaxf(v0, 0.0f);
        o.h[1] = (_Float16)fmaxf(v1, 0.0f);
        *(unsigned*)((_Float16*)aggv + (size_t)node * HID + f0) = o.u;
    } else {
        *(float2*)((float*)aggv + (size_t)node * HID + f0) = make_float2(v0, v1);
    }
}

// ---------------------------------------------------------------- launch
extern "C" void kernel_launch(void* const* d_in, const int* in_sizes, int n_in,
                              void* d_out, int out_size, void* d_ws, size_t ws_size,
                              hipStream_t stream)
{
    const float* x  = (const float*)d_in[0];
    const float* W1 = (const float*)d_in[1];
    const float* b1 = (const float*)d_in[2];
    const float* W2 = (const float*)d_in[3];
    const float* b2 = (const float*)d_in[4];
    const float* W3 = (const float*)d_in[5];
    const float* b3 = (const float*)d_in[6];
    const int*   ei = (const int*)d_in[7];
    const int* row  = ei;            // sources
    const int* colv = ei + NE;       // targets
    float* out = (float*)d_out;

    _Float16* h16 = (_Float16*)d_ws;                  // NN*HID
    _Float16* a16 = h16 + (size_t)NN * HID;           // NN*HID
    _Float16* wt  = a16 + (size_t)NN * HID;           // 3*128*128
    int*   degi    = (int*)(wt + 3 * 128 * 128);      // NN
    float* dinv    = (float*)(degi + NN);             // NN
    int*   rowptr  = (int*)(dinv + NN);               // NN+1
    int*   cursor  = rowptr + NN + 1;                 // NN
    int*   bsum    = cursor + NN;                     // 512
    int*   csr_src = bsum + 512;                      // NE

    const int TB = 256;
    const int nScanBlocks = (NN + 255) / 256;         // 391

    k_wprep<<<384, 128, 0, stream>>>(W1, W2, W3, wt);
    hipMemsetAsync(degi, 0, NN * sizeof(int), stream);
    k_degi      <<<(NE + TB - 1) / TB, TB, 0, stream>>>(colv, degi, NE);
    k_blocksum  <<<nScanBlocks, 256, 0, stream>>>(degi, dinv, bsum, NN);
    k_scan_bsum <<<1, 512, 0, stream>>>(bsum, nScanBlocks);
    k_scan_apply<<<nScanBlocks, 256, 0, stream>>>(degi, bsum, rowptr, cursor, NN);
    k_fill_csr  <<<(NE + TB - 1) / TB, TB, 0, stream>>>(row, colv, cursor, csr_src, NE);

    const int gemmBlocks = (NN + 127) / 128;          // 782
    const int aggBlocks  = (NN + 3) / 4;              // 25000

    // layer 1: h16 = dinv*(x@W1) ; a16 = relu(agg(h16)+b1)
    k_gemm<float><<<gemmBlocks, TB, 0, stream>>>(x, wt, dinv, h16, NN);
    k_aggregate<0><<<aggBlocks, TB, 0, stream>>>(h16, csr_src, rowptr, dinv, b1, a16, NN);
    // layer 2: h16 = dinv*(a16@W2) ; a16 = relu(agg(h16)+b2)
    k_gemm<_Float16><<<gemmBlocks, TB, 0, stream>>>(a16, wt + (1 << 14), dinv, h16, NN);
    k_aggregate<0><<<aggBlocks, TB, 0, stream>>>(h16, csr_src, rowptr, dinv, b2, a16, NN);
    // layer 3: h16 = dinv*(a16@W3) ; out = agg(h16) + b3
    k_gemm<_Float16><<<gemmBlocks, TB, 0, stream>>>(a16, wt + (2 << 14), dinv, h16, NN);
    k_aggregate<1><<<aggBlocks, TB, 0, stream>>>(h16, csr_src, rowptr, dinv, b3, out, NN);
}